// Round 7
// baseline (361.211 us; speedup 1.0000x reference)
//
#include <hip/hip_runtime.h>
#include <stdint.h>

// ---------------------------------------------------------------------------
// SelfAttention: out[b,n,d] = ( softmax( (X^T Wk)(X^T Wq)^T / 32 ) (X^T Wv) )^T
// B=16, N=D=1024.
//
// R5 algebra: kq = xT (Wk Wq^T) x -> 4 big GEMMs (tmp, vvT, kq(P), out).
// R6a fusion: softmax folded into GEMM epilogues (EPI=2 exp+Spart, EPI=3 /S).
// R7 gemm: 256x128 tile, BK=64, 512thr/8 waves, 48 KiB single-buffer LDS,
//   2 blocks/CU co-resident (cross-block overlap hides drain).
// R10 (this): per-CU arithmetic says R7 is LDS-pipe-bound (256 KB reads +
//   96 KB DMA writes per K-tile-pair ~ 43 B/cyc ~ shared-pipe ceiling).
//   For the two gemms whose one operand is a small batch-shared weight
//   panel (tmp: B=W2T 2MB; vvT: A=Wtv 2MB), read that operand's fragments
//   DIRECTLY from global/L2 (GOP template param), skipping LDS entirely:
//   halves LDS reads, cuts DMA writes, and the frag loads issue before
//   __syncthreads so L2 latency overlaps the already-exposed DMA drain.
//   Per-instr footprint: 16 rows x one 64B line (chunks 0..3 -> bytes 0..63).
// ---------------------------------------------------------------------------

typedef __bf16 bf16x8_t __attribute__((ext_vector_type(8)));
typedef float  f32x4_t  __attribute__((ext_vector_type(4)));

typedef __attribute__((address_space(3))) uint32_t as3_u32;
typedef __attribute__((address_space(1))) uint32_t as1_u32;

__device__ __forceinline__ void async_copy16(const void* g, const void* l) {
  __builtin_amdgcn_global_load_lds((const as1_u32*)(uintptr_t)g,
                                   (as3_u32*)(uint32_t)(uintptr_t)l,
                                   16, 0, 0);
}

__device__ __forceinline__ uint16_t f2bf(float f) {  // RNE
  uint32_t x = __float_as_uint(f);
  return (uint16_t)((x + 0x7fffu + ((x >> 16) & 1u)) >> 16);
}
__device__ __forceinline__ float bf2f(uint16_t b) {
  return __uint_as_float(((uint32_t)b) << 16);
}

// C[m,n] = alpha * sum_k A[m,k] * B[n,k].  M=N=K=1024 fixed per batch slice.
// Tile 256(M) x 128(N), BK=64.  512 blocks x 512 threads.
// EPI: 0 = bf16 C*alpha;  2 = bf16 exp(C*alpha) + Spart row partials;
//      3 = f32 C*alpha/S[col] (S = sum of 16 Spart slots).
// GOP: 0 = both operands LDS-staged; 1 = A direct-from-global (weight A);
//      2 = B direct-from-global (weight B).
template <int EPI, int GOP>
__global__ __launch_bounds__(512, 4)
void gemm_bt256x128(const uint16_t* __restrict__ A,
                    const uint16_t* __restrict__ B,
                    void* __restrict__ Cv, size_t sA, size_t sB, size_t sC,
                    float alpha, float* __restrict__ Sp)
{
  __shared__ __align__(16) char smem[49152];
  char* As = smem;            // 256 x 64 bf16 = 32768 B
  char* Bs = smem + 32768;    // 128 x 64 bf16 = 16384 B

  // ---- XCD swizzle: lid%8 = XCD; 2 batches per XCD, 4x8 tiles per batch ----
  const int lid  = blockIdx.x;
  const int xcd  = lid & 7;
  const int slot = lid >> 3;            // 0..63
  const int z    = (xcd << 1) | (slot >> 5);
  const int t32  = slot & 31;
  const int bm0  = (t32 >> 3) << 8;     // 0,256,512,768
  const int bn0  = (t32 & 7) << 7;      // 0..896 step 128

  A += (size_t)z * sA + ((size_t)bm0 << 10);
  B += (size_t)z * sB + ((size_t)bn0 << 10);

  const int t    = threadIdx.x;
  const int lane = t & 63;
  const int w    = t >> 6;              // 0..7
  const int q    = lane >> 4;
  const int r16  = lane & 15;
  const int wm   = (w >> 1) << 6;       // 0,64,128,192
  const int wn   = (w & 1) << 6;        // 0,64

  // ---- staging constants: row pitch 128 B, slot cp holds chunk cp^(row&7) --
  const int g0  = t >> 3;               // 0..63
  const int cp  = t & 7;
  const int ce  = (cp ^ (g0 & 7)) << 3; // (g0+64s)&7 == g0&7, so ce is const
  const int so  = (g0 << 7) + (cp << 4);
  const uint16_t* Ag = A + ((size_t)g0 << 10) + ce;
  const uint16_t* Bg = B + ((size_t)g0 << 10) + ce;

  f32x4_t acc[4][4];
#pragma unroll
  for (int i = 0; i < 4; i++)
#pragma unroll
    for (int j = 0; j < 4; j++) acc[i][j] = (f32x4_t){0.f, 0.f, 0.f, 0.f};

  bf16x8_t gf[4][2];   // global-direct fragments (A-side if GOP==1, B if 2)

  for (int k0 = 0; k0 < 1024; k0 += 64) {
    // ---- stage the LDS-resident operand(s) via DMA ----
    if constexpr (GOP != 1) {
#pragma unroll
      for (int s = 0; s < 4; ++s)
        async_copy16(Ag + (((size_t)s << 6) << 10) + k0, As + so + (s << 13));
    }
    if constexpr (GOP != 2) {
#pragma unroll
      for (int s = 0; s < 2; ++s)
        async_copy16(Bg + (((size_t)s << 6) << 10) + k0, Bs + so + (s << 13));
    }
    // ---- global-direct fragments: issue BEFORE the barrier so L2 latency
    //      overlaps the DMA drain.  chunk c = (kk<<2)+q, bytes c*16 (no swz).
    if constexpr (GOP == 1) {
#pragma unroll
      for (int mi = 0; mi < 4; ++mi)
#pragma unroll
        for (int kk = 0; kk < 2; ++kk)
          gf[mi][kk] = *(const bf16x8_t*)(
              A + ((size_t)(wm + (mi << 4) + r16) << 10) + k0
                + (((kk << 2) + q) << 3));
    } else if constexpr (GOP == 2) {
#pragma unroll
      for (int ni = 0; ni < 4; ++ni)
#pragma unroll
        for (int kk = 0; kk < 2; ++kk)
          gf[ni][kk] = *(const bf16x8_t*)(
              B + ((size_t)(wn + (ni << 4) + r16) << 10) + k0
                + (((kk << 2) + q) << 3));
    }
    __syncthreads();   // drains DMA + our global frag loads (vmcnt 0)

#pragma unroll
    for (int kk = 0; kk < 2; ++kk) {
      bf16x8_t af[4], bfr[4];
      if constexpr (GOP != 1) {
#pragma unroll
        for (int mi = 0; mi < 4; ++mi) {
          const int m = wm + (mi << 4) + r16;
          const int c = (kk << 2) + q;
          af[mi] = *(const bf16x8_t*)(As + (m << 7) + ((c ^ (m & 7)) << 4));
        }
      }
      if constexpr (GOP != 2) {
#pragma unroll
        for (int ni = 0; ni < 4; ++ni) {
          const int n = wn + (ni << 4) + r16;
          const int c = (kk << 2) + q;
          bfr[ni] = *(const bf16x8_t*)(Bs + (n << 7) + ((c ^ (n & 7)) << 4));
        }
      }
      __builtin_amdgcn_s_setprio(1);
#pragma unroll
      for (int mi = 0; mi < 4; ++mi)
#pragma unroll
        for (int ni = 0; ni < 4; ++ni) {
          const bf16x8_t av = (GOP == 1) ? gf[mi][kk] : af[mi];
          const bf16x8_t bv = (GOP == 2) ? gf[ni][kk] : bfr[ni];
          acc[mi][ni] = __builtin_amdgcn_mfma_f32_16x16x32_bf16(
              av, bv, acc[mi][ni], 0, 0, 0);
        }
      __builtin_amdgcn_s_setprio(0);
    }
    __syncthreads();
  }

  // ---- epilogue.  C/D layout: col=lane&15, row=q*4+r (verified m89/m91) ----
  if constexpr (EPI == 3) {
    // f32 out, scaled by 1/S[col]; S = sum of 16 Spart slots per column.
    float inv[4];
#pragma unroll
    for (int ni = 0; ni < 4; ++ni) {
      const int c = bn0 + wn + (ni << 4) + r16;
      float S = 0.f;
#pragma unroll
      for (int p = 0; p < 16; ++p)
        S += Sp[((size_t)p << 14) + ((size_t)z << 10) + c];
      inv[ni] = 1.0f / S;
    }
    float* C = (float*)Cv + (size_t)z * sC;
#pragma unroll
    for (int mi = 0; mi < 4; ++mi)
#pragma unroll
      for (int ni = 0; ni < 4; ++ni)
#pragma unroll
        for (int r = 0; r < 4; ++r) {
          const int row = bm0 + wm + (mi << 4) + (q << 2) + r;
          const int col = bn0 + wn + (ni << 4) + r16;
          C[((size_t)row << 10) + col] = acc[mi][ni][r] * alpha * inv[ni];
        }
  } else {
    // bf16 out via per-wave-private LDS staging -> full 128-B row stores.
    // EPI==2 additionally applies exp() and emits per-row partial sums.
    float* reg = (float*)smem + (size_t)w * 1056;   // 16 x 66 floats
    uint16_t* C = (uint16_t*)Cv + (size_t)z * sC;
    float* SpW = Sp + ((size_t)(((bn0 >> 7) << 1) + (w & 1)) << 14)
                    + ((size_t)z << 10);
#pragma unroll
    for (int mi = 0; mi < 4; ++mi) {
      if constexpr (EPI == 2) {
        float ev[4][4];
#pragma unroll
        for (int ni = 0; ni < 4; ++ni)
#pragma unroll
          for (int r = 0; r < 4; ++r) {
            ev[ni][r] = __expf(acc[mi][ni][r] * alpha);
            reg[((q << 2) + r) * 66 + (ni << 4) + r16] = ev[ni][r];
          }
#pragma unroll
        for (int r = 0; r < 4; ++r) {
          float s = ev[0][r] + ev[1][r] + ev[2][r] + ev[3][r];
          s += __shfl_xor(s, 1, 16);
          s += __shfl_xor(s, 2, 16);
          s += __shfl_xor(s, 4, 16);
          s += __shfl_xor(s, 8, 16);
          if (r16 == 0)
            SpW[bm0 + wm + (mi << 4) + (q << 2) + r] = s;
        }
      } else {
#pragma unroll
        for (int ni = 0; ni < 4; ++ni)
#pragma unroll
          for (int r = 0; r < 4; ++r)
            reg[((q << 2) + r) * 66 + (ni << 4) + r16] = acc[mi][ni][r] * alpha;
      }
#pragma unroll
      for (int it = 0; it < 8; ++it) {
        const int rr = (it << 1) + (lane >> 5);     // 0..15
        const int cc = (lane & 31) << 1;            // 0..62
        const float2 v = *(const float2*)(reg + rr * 66 + cc);
        const uint32_t p = (uint32_t)f2bf(v.x) | ((uint32_t)f2bf(v.y) << 16);
        const int row = bm0 + wm + (mi << 4) + rr;
        const int col = bn0 + wn + cc;
        *(uint32_t*)(C + ((size_t)row << 10) + col) = p;
      }
    }
  }
}

// Split-K GEMM for W2T = Wq Wk^T: P[slice][m,n] = sum_{k in slice} A[m,k]B[n,k]
// M=N=1024, K=1024, splitK=4 (256 k each).  grid 256 x 256thr.
__global__ __launch_bounds__(256, 4)
void gemm128_splitk(const uint16_t* __restrict__ A, const uint16_t* __restrict__ B,
                    float* __restrict__ P)
{
  __shared__ __align__(16) char smem[32768];
  char* As = smem;
  char* Bs = smem + 16384;

  const int slice = blockIdx.x >> 6;
  const int tile  = blockIdx.x & 63;
  const int bm0   = (tile >> 3) << 7;
  const int bn0   = (tile & 7) << 7;
  const int koff  = slice << 8;

  const int t    = threadIdx.x;
  const int lane = t & 63;
  const int w    = t >> 6;
  const int q    = lane >> 4;
  const int r16  = lane & 15;
  const int wm   = (w >> 1) << 6;
  const int wn   = (w & 1) << 6;

  f32x4_t acc[4][4];
#pragma unroll
  for (int i = 0; i < 4; i++)
#pragma unroll
    for (int j = 0; j < 4; j++) acc[i][j] = (f32x4_t){0.f, 0.f, 0.f, 0.f};

  for (int k0 = koff; k0 < koff + 256; k0 += 64) {
#pragma unroll
    for (int i = 0; i < 4; i++) {
      const int o  = (i << 12) + (t << 4);
      const int m  = o >> 7;
      const int cp = (o >> 4) & 7;
      const int c  = cp ^ (m & 7);
      async_copy16(A + (size_t)(bm0 + m) * 1024 + (size_t)(k0 + (c << 3)), As + o);
      async_copy16(B + (size_t)(bn0 + m) * 1024 + (size_t)(k0 + (c << 3)), Bs + o);
    }
    __syncthreads();
#pragma unroll
    for (int kk = 0; kk < 2; kk++) {
      bf16x8_t af[4], bfr[4];
#pragma unroll
      for (int mi = 0; mi < 4; mi++) {
        const int m = wm + (mi << 4) + r16;
        const int c = (kk << 2) + q;
        af[mi] = *(const bf16x8_t*)(As + (m << 7) + ((c ^ (m & 7)) << 4));
      }
#pragma unroll
      for (int ni = 0; ni < 4; ni++) {
        const int n = wn + (ni << 4) + r16;
        const int c = (kk << 2) + q;
        bfr[ni] = *(const bf16x8_t*)(Bs + (n << 7) + ((c ^ (n & 7)) << 4));
      }
#pragma unroll
      for (int mi = 0; mi < 4; mi++)
#pragma unroll
        for (int ni = 0; ni < 4; ni++)
          acc[mi][ni] = __builtin_amdgcn_mfma_f32_16x16x32_bf16(
              af[mi], bfr[ni], acc[mi][ni], 0, 0, 0);
    }
    __syncthreads();
  }

  float* C = P + (size_t)slice * (1024u * 1024u);
#pragma unroll
  for (int mi = 0; mi < 4; mi++)
#pragma unroll
    for (int ni = 0; ni < 4; ni++)
#pragma unroll
      for (int r = 0; r < 4; r++) {
        const int row = bm0 + wm + (mi << 4) + (q << 2) + r;
        const int col = bn0 + wn + (ni << 4) + r16;
        C[((size_t)row << 10) + col] = acc[mi][ni][r];
      }
}

// W2Tc = bf16( P[0] + P[1] + P[2] + P[3] ).  grid 1024 x 256thr, 4 elems/thr.
__global__ __launch_bounds__(256)
void reduce_w2t(const float* __restrict__ P, uint16_t* __restrict__ W)
{
  const size_t i4 = (((size_t)blockIdx.x << 8) + threadIdx.x) << 2;
  const float4 a = *(const float4*)(P + i4);
  const float4 b = *(const float4*)(P + (1u << 20) + i4);
  const float4 c = *(const float4*)(P + (2u << 20) + i4);
  const float4 d = *(const float4*)(P + (3u << 20) + i4);
  ushort4 r;
  r.x = f2bf(a.x + b.x + c.x + d.x);
  r.y = f2bf(a.y + b.y + c.y + d.y);
  r.z = f2bf(a.z + b.z + c.z + d.z);
  r.w = f2bf(a.w + b.w + c.w + d.w);
  *(ushort4*)(W + i4) = r;
}

// z=0: cast Wk->o0 (row-major, float4->ushort4); z=1: same for Wq;
// z=2: transpose-cast Wv->o2 (32x32 LDS tile).  256 threads, 1D.
__global__ __launch_bounds__(256)
void prep_w(const float* __restrict__ w0, const float* __restrict__ w1,
            const float* __restrict__ w2, uint16_t* __restrict__ o0,
            uint16_t* __restrict__ o1, uint16_t* __restrict__ o2)
{
  __shared__ float tile[32][33];
  const int z = blockIdx.z;
  const int c0 = blockIdx.x << 5;
  const int r0 = blockIdx.y << 5;
  const int t = threadIdx.x;
  if (z < 2) {
    const float* src = z ? w1 : w0;
    uint16_t* dst = z ? o1 : o0;
    const int row = t >> 3;              // 0..31
    const int c4  = (t & 7) << 2;        // 0,4,...,28
    const float4 v =
        *(const float4*)(src + (size_t)(r0 + row) * 1024 + c0 + c4);
    ushort4 u;
    u.x = f2bf(v.x); u.y = f2bf(v.y); u.z = f2bf(v.z); u.w = f2bf(v.w);
    *(ushort4*)(dst + (size_t)(r0 + row) * 1024 + c0 + c4) = u;
  } else {
    const int tx = t & 31, ty = t >> 5;  // (32,8)
#pragma unroll
    for (int i = 0; i < 32; i += 8)
      tile[ty + i][tx] = w2[(size_t)(r0 + ty + i) * 1024 + (c0 + tx)];
    __syncthreads();
#pragma unroll
    for (int i = 0; i < 32; i += 8)
      o2[(size_t)(c0 + ty + i) * 1024 + (r0 + tx)] = f2bf(tile[tx][ty + i]);
  }
}

// dst[c][r] = bf16(src[r][c]) for 1024x1024 f32 batches.  64x64 tiles,
// float4 loads, 16B packed bf16 stores.
__global__ __launch_bounds__(256)
void transpose_cast64(const float* __restrict__ src, uint16_t* __restrict__ dst,
                      size_t sStride, size_t dStride)
{
  __shared__ float tile[64][65];
  const int z = blockIdx.z;
  src += (size_t)z * sStride;
  dst += (size_t)z * dStride;
  const int c0 = blockIdx.x << 6;
  const int r0 = blockIdx.y << 6;
  const int t = threadIdx.x;
  const int row  = t >> 4;              // 0..15
  const int col4 = (t & 15) << 2;       // 0,4,...,60
#pragma unroll
  for (int i = 0; i < 4; ++i) {
    const float4 v = *(const float4*)(
        src + (size_t)(r0 + row + (i << 4)) * 1024 + c0 + col4);
    float* tp = &tile[row + (i << 4)][col4];
    tp[0] = v.x; tp[1] = v.y; tp[2] = v.z; tp[3] = v.w;
  }
  __syncthreads();
#pragma unroll
  for (int p = 0; p < 2; ++p) {
    const int idx = (p << 8) + t;
    const int c  = idx >> 3;            // 0..63
    const int s8 = (idx & 7) << 3;      // 0,8,...,56
    uint32_t u0 = (uint32_t)f2bf(tile[s8 + 0][c]) |
                  ((uint32_t)f2bf(tile[s8 + 1][c]) << 16);
    uint32_t u1 = (uint32_t)f2bf(tile[s8 + 2][c]) |
                  ((uint32_t)f2bf(tile[s8 + 3][c]) << 16);
    uint32_t u2 = (uint32_t)f2bf(tile[s8 + 4][c]) |
                  ((uint32_t)f2bf(tile[s8 + 5][c]) << 16);
    uint32_t u3 = (uint32_t)f2bf(tile[s8 + 6][c]) |
                  ((uint32_t)f2bf(tile[s8 + 7][c]) << 16);
    uint4 pk; pk.x = u0; pk.y = u1; pk.z = u2; pk.w = u3;
    *(uint4*)(dst + (size_t)(c0 + c) * 1024 + r0 + s8) = pk;
  }
}

extern "C" void kernel_launch(void* const* d_in, const int* in_sizes, int n_in,
                              void* d_out, int out_size, void* d_ws, size_t ws_size,
                              hipStream_t stream)
{
  const float* x  = (const float*)d_in[0];
  const float* wk = (const float*)d_in[1];
  const float* wq = (const float*)d_in[2];
  const float* wv = (const float*)d_in[3];
  float* out = (float*)d_out;

  constexpr int BB = 16, N = 1024, D = 1024;
  constexpr size_t DN = (size_t)D * N;

  // workspace layout (bytes)           size    lifetime
  // xT    @ 0                          32 MB   through kq gemm
  // Wkc   @ 32M, Wqc @ 34M, Wtv @ 36M   6 MB
  // W2Tc  @ 38M                         2 MB   dead after tmp gemm
  // W2p   @ 40M                        16 MB   dead after reduce
  // tmp   @ 56M                        32 MB   dead after kq gemm
  // vvT   @ 88M                        32 MB
  // P(kq) @ 120M                       32 MB   exp(kq/32), bf16
  // Spart @ 152M                        1 MB   16 slots x 16 x 1024 f32
  char* ws = (char*)d_ws;
  uint16_t* xT   = (uint16_t*)(ws);
  uint16_t* Wkc  = (uint16_t*)(ws + (32ull << 20));
  uint16_t* Wqc  = (uint16_t*)(ws + (34ull << 20));
  uint16_t* Wtv  = (uint16_t*)(ws + (36ull << 20));
  uint16_t* W2Tc = (uint16_t*)(ws + (38ull << 20));
  float*    W2p  = (float*)   (ws + (40ull << 20));
  uint16_t* tmp  = (uint16_t*)(ws + (56ull << 20));
  uint16_t* vvT  = (uint16_t*)(ws + (88ull << 20));
  uint16_t* P    = (uint16_t*)(ws + (120ull << 20));
  float*    Spart= (float*)   (ws + (152ull << 20));

  // weights: cast Wk, Wq; transpose-cast Wv
  prep_w<<<dim3(N / 32, N / 32, 3), 256, 0, stream>>>(wk, wq, wv, Wkc, Wqc, Wtv);
  // W2T[j,i] = sum_n Wq[j,n] Wk[i,n]  (split-K=4 partials, then reduce+cast)
  gemm128_splitk<<<256, 256, 0, stream>>>(Wqc, Wkc, W2p);
  reduce_w2t<<<1024, 256, 0, stream>>>(W2p, W2Tc);
  // xT[b][d][n] = x[b][n][d]
  transpose_cast64<<<dim3(D / 64, N / 64, BB), 256, 0, stream>>>(x, xT, DN, DN);
  // tmp[b][d][j] = sum_i xT[b][d][i] * W2T[j][i]   (B=W2T direct-from-L2)
  gemm_bt256x128<0, 2><<<512, 512, 0, stream>>>(xT, W2Tc, tmp, DN, 0, DN, 1.0f, Spart);
  // vvT[b][n][d] = sum_n' Wtv[n][n'] * xT[b][d][n']   (A=Wtv direct-from-L2)
  gemm_bt256x128<0, 1><<<512, 512, 0, stream>>>(Wtv, xT, vvT, 0, DN, DN, 1.0f, Spart);
  // P[b][d][e] = exp( (1/32) sum_j tmp[b][d][j] * xT[b][e][j] ),  + Spart
  gemm_bt256x128<2, 0><<<512, 512, 0, stream>>>(tmp, xT, P, DN, DN, DN, 0.03125f, Spart);
  // out[b][n][d] = ( sum_e vvT[b][n][e] * P[b][d][e] ) / S[b][d]
  gemm_bt256x128<3, 0><<<512, 512, 0, stream>>>(vvT, P, out, DN, DN, DN, 1.0f, Spart);
}

// Round 8
// 285.771 us; speedup vs baseline: 1.2640x; 1.2640x over previous
//
#include <hip/hip_runtime.h>
#include <stdint.h>

// ---------------------------------------------------------------------------
// SelfAttention: out[b,n,d] = ( softmax( (X^T Wk)(X^T Wq)^T / 32 ) (X^T Wv) )^T
// B=16, N=D=1024.
//
// R5 algebra: kq = xT (Wk Wq^T) x -> 4 big GEMMs (tmp, vvT, kq(P), out).
// R6a fusion: softmax folded into GEMM epilogues (EPI=2 exp+Spart, EPI=3 /S).
// R7 gemm (plateau, kept verbatim): 256x128 tile, BK=64, 512thr/8 waves,
//   48 KiB single-buffer LDS; cross-block overlap hides the per-tile
//   vmcnt(0)+barrier drain.  41 us/gemm after 5 schedule variants
//   (R4/R5/R6b/R8 all null or regress) and LDS-bypass (R10, -2x).
// R11 (this): revert R10; merge the two INDEPENDENT gemms (tmp, vvT - both
//   consume only xT + a 2MB weight) into ONE 1024-block launch: 48KB LDS ->
//   3 blocks/CU co-resident (grid was the 2/CU limiter at 512), deepening
//   the cross-block overlap and fusing the two gemms' dispatch tails.
// ---------------------------------------------------------------------------

typedef __bf16 bf16x8_t __attribute__((ext_vector_type(8)));
typedef float  f32x4_t  __attribute__((ext_vector_type(4)));

typedef __attribute__((address_space(3))) uint32_t as3_u32;
typedef __attribute__((address_space(1))) uint32_t as1_u32;

__device__ __forceinline__ void async_copy16(const void* g, const void* l) {
  __builtin_amdgcn_global_load_lds((const as1_u32*)(uintptr_t)g,
                                   (as3_u32*)(uint32_t)(uintptr_t)l,
                                   16, 0, 0);
}

__device__ __forceinline__ uint16_t f2bf(float f) {  // RNE
  uint32_t x = __float_as_uint(f);
  return (uint16_t)((x + 0x7fffu + ((x >> 16) & 1u)) >> 16);
}
__device__ __forceinline__ float bf2f(uint16_t b) {
  return __uint_as_float(((uint32_t)b) << 16);
}

// C[m,n] = alpha * sum_k A[m,k] * B[n,k].  M=N=K=1024 fixed per batch slice.
// Tile 256(M) x 128(N), BK=64.  512 logical blocks x 512 threads.
// EPI: 0 = bf16 C*alpha;  2 = bf16 exp(C*alpha) + Spart row partials;
//      3 = f32 C*alpha/S[col] (S = sum of 16 Spart slots).
template <int EPI>
__device__ __forceinline__ void gemm_body(
    const uint16_t* __restrict__ A, const uint16_t* __restrict__ B,
    void* __restrict__ Cv, size_t sA, size_t sB, size_t sC,
    float alpha, float* __restrict__ Sp, int lid, char* smem)
{
  char* As = smem;            // 256 x 64 bf16 = 32768 B
  char* Bs = smem + 32768;    // 128 x 64 bf16 = 16384 B

  // ---- XCD swizzle: lid%8 = XCD; 2 batches per XCD, 4x8 tiles per batch ----
  const int xcd  = lid & 7;
  const int slot = lid >> 3;            // 0..63
  const int z    = (xcd << 1) | (slot >> 5);
  const int t32  = slot & 31;
  const int bm0  = (t32 >> 3) << 8;     // 0,256,512,768
  const int bn0  = (t32 & 7) << 7;      // 0..896 step 128

  A += (size_t)z * sA + ((size_t)bm0 << 10);
  B += (size_t)z * sB + ((size_t)bn0 << 10);

  const int t    = threadIdx.x;
  const int lane = t & 63;
  const int w    = t >> 6;              // 0..7
  const int q    = lane >> 4;
  const int r16  = lane & 15;
  const int wm   = (w >> 1) << 6;       // 0,64,128,192
  const int wn   = (w & 1) << 6;        // 0,64

  // ---- staging constants: row pitch 128 B, slot cp holds chunk cp^(row&7) --
  const int g0  = t >> 3;               // 0..63
  const int cp  = t & 7;
  const int ce  = (cp ^ (g0 & 7)) << 3; // (g0+64s)&7 == g0&7, so ce is const
  const int so  = (g0 << 7) + (cp << 4);
  const uint16_t* Ag = A + ((size_t)g0 << 10) + ce;
  const uint16_t* Bg = B + ((size_t)g0 << 10) + ce;

  f32x4_t acc[4][4];
#pragma unroll
  for (int i = 0; i < 4; i++)
#pragma unroll
    for (int j = 0; j < 4; j++) acc[i][j] = (f32x4_t){0.f, 0.f, 0.f, 0.f};

  for (int k0 = 0; k0 < 1024; k0 += 64) {
    // A: 4 x 16B per thread (rows g0+64s); B: 2 x 16B (rows g0+64s).
#pragma unroll
    for (int s = 0; s < 4; ++s)
      async_copy16(Ag + (((size_t)s << 6) << 10) + k0, As + so + (s << 13));
#pragma unroll
    for (int s = 0; s < 2; ++s)
      async_copy16(Bg + (((size_t)s << 6) << 10) + k0, Bs + so + (s << 13));
    __syncthreads();   // full drain (vmcnt 0); hidden by co-resident blocks

#pragma unroll
    for (int kk = 0; kk < 2; ++kk) {
      bf16x8_t af[4], bfr[4];
#pragma unroll
      for (int mi = 0; mi < 4; ++mi) {
        const int m = wm + (mi << 4) + r16;
        const int c = (kk << 2) + q;
        af[mi] = *(const bf16x8_t*)(As + (m << 7) + ((c ^ (m & 7)) << 4));
      }
#pragma unroll
      for (int ni = 0; ni < 4; ++ni) {
        const int n = wn + (ni << 4) + r16;
        const int c = (kk << 2) + q;
        bfr[ni] = *(const bf16x8_t*)(Bs + (n << 7) + ((c ^ (n & 7)) << 4));
      }
      __builtin_amdgcn_s_setprio(1);
#pragma unroll
      for (int mi = 0; mi < 4; ++mi)
#pragma unroll
        for (int ni = 0; ni < 4; ++ni)
          acc[mi][ni] = __builtin_amdgcn_mfma_f32_16x16x32_bf16(
              af[mi], bfr[ni], acc[mi][ni], 0, 0, 0);
      __builtin_amdgcn_s_setprio(0);
    }
    __syncthreads();
  }

  // ---- epilogue.  C/D layout: col=lane&15, row=q*4+r (verified m89/m91) ----
  if constexpr (EPI == 3) {
    // f32 out, scaled by 1/S[col]; S = sum of 16 Spart slots per column.
    float inv[4];
#pragma unroll
    for (int ni = 0; ni < 4; ++ni) {
      const int c = bn0 + wn + (ni << 4) + r16;
      float S = 0.f;
#pragma unroll
      for (int p = 0; p < 16; ++p)
        S += Sp[((size_t)p << 14) + ((size_t)z << 10) + c];
      inv[ni] = 1.0f / S;
    }
    float* C = (float*)Cv + (size_t)z * sC;
#pragma unroll
    for (int mi = 0; mi < 4; ++mi)
#pragma unroll
      for (int ni = 0; ni < 4; ++ni)
#pragma unroll
        for (int r = 0; r < 4; ++r) {
          const int row = bm0 + wm + (mi << 4) + (q << 2) + r;
          const int col = bn0 + wn + (ni << 4) + r16;
          C[((size_t)row << 10) + col] = acc[mi][ni][r] * alpha * inv[ni];
        }
  } else {
    // bf16 out via per-wave-private LDS staging -> full 128-B row stores.
    // EPI==2 additionally applies exp() and emits per-row partial sums.
    float* reg = (float*)smem + (size_t)w * 1056;   // 16 x 66 floats
    uint16_t* C = (uint16_t*)Cv + (size_t)z * sC;
    float* SpW = Sp + ((size_t)(((bn0 >> 7) << 1) + (w & 1)) << 14)
                    + ((size_t)z << 10);
#pragma unroll
    for (int mi = 0; mi < 4; ++mi) {
      if constexpr (EPI == 2) {
        float ev[4][4];
#pragma unroll
        for (int ni = 0; ni < 4; ++ni)
#pragma unroll
          for (int r = 0; r < 4; ++r) {
            ev[ni][r] = __expf(acc[mi][ni][r] * alpha);
            reg[((q << 2) + r) * 66 + (ni << 4) + r16] = ev[ni][r];
          }
#pragma unroll
        for (int r = 0; r < 4; ++r) {
          float s = ev[0][r] + ev[1][r] + ev[2][r] + ev[3][r];
          s += __shfl_xor(s, 1, 16);
          s += __shfl_xor(s, 2, 16);
          s += __shfl_xor(s, 4, 16);
          s += __shfl_xor(s, 8, 16);
          if (r16 == 0)
            SpW[bm0 + wm + (mi << 4) + (q << 2) + r] = s;
        }
      } else {
#pragma unroll
        for (int ni = 0; ni < 4; ++ni)
#pragma unroll
          for (int r = 0; r < 4; ++r)
            reg[((q << 2) + r) * 66 + (ni << 4) + r16] = acc[mi][ni][r] * alpha;
      }
#pragma unroll
      for (int it = 0; it < 8; ++it) {
        const int rr = (it << 1) + (lane >> 5);     // 0..15
        const int cc = (lane & 31) << 1;            // 0..62
        const float2 v = *(const float2*)(reg + rr * 66 + cc);
        const uint32_t p = (uint32_t)f2bf(v.x) | ((uint32_t)f2bf(v.y) << 16);
        const int row = bm0 + wm + (mi << 4) + rr;
        const int col = bn0 + wn + cc;
        *(uint32_t*)(C + ((size_t)row << 10) + col) = p;
      }
    }
  }
}

template <int EPI>
__global__ __launch_bounds__(512, 4)
void gemm_bt256x128(const uint16_t* __restrict__ A,
                    const uint16_t* __restrict__ B,
                    void* __restrict__ Cv, size_t sA, size_t sB, size_t sC,
                    float alpha, float* __restrict__ Sp)
{
  __shared__ __align__(16) char smem[49152];
  gemm_body<EPI>(A, B, Cv, sA, sB, sC, alpha, Sp, blockIdx.x, smem);
}

// Two independent EPI=0 gemms in one 1024-block launch (blocks 0-511 -> job0,
// 512-1023 -> job1).  48KB LDS -> 3 blocks/CU co-resident (vs 2 grid-limited).
__global__ __launch_bounds__(512, 4)
void gemm_pair(const uint16_t* __restrict__ A0, const uint16_t* __restrict__ B0,
               void* __restrict__ C0, size_t sA0, size_t sB0, size_t sC0,
               const uint16_t* __restrict__ A1, const uint16_t* __restrict__ B1,
               void* __restrict__ C1, size_t sA1, size_t sB1, size_t sC1)
{
  __shared__ __align__(16) char smem[49152];
  const int lid = blockIdx.x;
  if (lid < 512)
    gemm_body<0>(A0, B0, C0, sA0, sB0, sC0, 1.0f, nullptr, lid, smem);
  else
    gemm_body<0>(A1, B1, C1, sA1, sB1, sC1, 1.0f, nullptr, lid - 512, smem);
}

// Split-K GEMM for W2T = Wq Wk^T: P[slice][m,n] = sum_{k in slice} A[m,k]B[n,k]
// M=N=1024, K=1024, splitK=4 (256 k each).  grid 256 x 256thr.
__global__ __launch_bounds__(256, 4)
void gemm128_splitk(const uint16_t* __restrict__ A, const uint16_t* __restrict__ B,
                    float* __restrict__ P)
{
  __shared__ __align__(16) char smem[32768];
  char* As = smem;
  char* Bs = smem + 16384;

  const int slice = blockIdx.x >> 6;
  const int tile  = blockIdx.x & 63;
  const int bm0   = (tile >> 3) << 7;
  const int bn0   = (tile & 7) << 7;
  const int koff  = slice << 8;

  const int t    = threadIdx.x;
  const int lane = t & 63;
  const int w    = t >> 6;
  const int q    = lane >> 4;
  const int r16  = lane & 15;
  const int wm   = (w >> 1) << 6;
  const int wn   = (w & 1) << 6;

  f32x4_t acc[4][4];
#pragma unroll
  for (int i = 0; i < 4; i++)
#pragma unroll
    for (int j = 0; j < 4; j++) acc[i][j] = (f32x4_t){0.f, 0.f, 0.f, 0.f};

  for (int k0 = koff; k0 < koff + 256; k0 += 64) {
#pragma unroll
    for (int i = 0; i < 4; i++) {
      const int o  = (i << 12) + (t << 4);
      const int m  = o >> 7;
      const int cp = (o >> 4) & 7;
      const int c  = cp ^ (m & 7);
      async_copy16(A + (size_t)(bm0 + m) * 1024 + (size_t)(k0 + (c << 3)), As + o);
      async_copy16(B + (size_t)(bn0 + m) * 1024 + (size_t)(k0 + (c << 3)), Bs + o);
    }
    __syncthreads();
#pragma unroll
    for (int kk = 0; kk < 2; kk++) {
      bf16x8_t af[4], bfr[4];
#pragma unroll
      for (int mi = 0; mi < 4; mi++) {
        const int m = wm + (mi << 4) + r16;
        const int c = (kk << 2) + q;
        af[mi] = *(const bf16x8_t*)(As + (m << 7) + ((c ^ (m & 7)) << 4));
      }
#pragma unroll
      for (int ni = 0; ni < 4; ni++) {
        const int n = wn + (ni << 4) + r16;
        const int c = (kk << 2) + q;
        bfr[ni] = *(const bf16x8_t*)(Bs + (n << 7) + ((c ^ (n & 7)) << 4));
      }
#pragma unroll
      for (int mi = 0; mi < 4; mi++)
#pragma unroll
        for (int ni = 0; ni < 4; ni++)
          acc[mi][ni] = __builtin_amdgcn_mfma_f32_16x16x32_bf16(
              af[mi], bfr[ni], acc[mi][ni], 0, 0, 0);
    }
    __syncthreads();
  }

  float* C = P + (size_t)slice * (1024u * 1024u);
#pragma unroll
  for (int mi = 0; mi < 4; mi++)
#pragma unroll
    for (int ni = 0; ni < 4; ni++)
#pragma unroll
      for (int r = 0; r < 4; r++) {
        const int row = bm0 + wm + (mi << 4) + (q << 2) + r;
        const int col = bn0 + wn + (ni << 4) + r16;
        C[((size_t)row << 10) + col] = acc[mi][ni][r];
      }
}

// W2Tc = bf16( P[0] + P[1] + P[2] + P[3] ).  grid 1024 x 256thr, 4 elems/thr.
__global__ __launch_bounds__(256)
void reduce_w2t(const float* __restrict__ P, uint16_t* __restrict__ W)
{
  const size_t i4 = (((size_t)blockIdx.x << 8) + threadIdx.x) << 2;
  const float4 a = *(const float4*)(P + i4);
  const float4 b = *(const float4*)(P + (1u << 20) + i4);
  const float4 c = *(const float4*)(P + (2u << 20) + i4);
  const float4 d = *(const float4*)(P + (3u << 20) + i4);
  ushort4 r;
  r.x = f2bf(a.x + b.x + c.x + d.x);
  r.y = f2bf(a.y + b.y + c.y + d.y);
  r.z = f2bf(a.z + b.z + c.z + d.z);
  r.w = f2bf(a.w + b.w + c.w + d.w);
  *(ushort4*)(W + i4) = r;
}

// z=0: cast Wk->o0 (row-major, float4->ushort4); z=1: same for Wq;
// z=2: transpose-cast Wv->o2 (32x32 LDS tile).  256 threads, 1D.
__global__ __launch_bounds__(256)
void prep_w(const float* __restrict__ w0, const float* __restrict__ w1,
            const float* __restrict__ w2, uint16_t* __restrict__ o0,
            uint16_t* __restrict__ o1, uint16_t* __restrict__ o2)
{
  __shared__ float tile[32][33];
  const int z = blockIdx.z;
  const int c0 = blockIdx.x << 5;
  const int r0 = blockIdx.y << 5;
  const int t = threadIdx.x;
  if (z < 2) {
    const float* src = z ? w1 : w0;
    uint16_t* dst = z ? o1 : o0;
    const int row = t >> 3;              // 0..31
    const int c4  = (t & 7) << 2;        // 0,4,...,28
    const float4 v =
        *(const float4*)(src + (size_t)(r0 + row) * 1024 + c0 + c4);
    ushort4 u;
    u.x = f2bf(v.x); u.y = f2bf(v.y); u.z = f2bf(v.z); u.w = f2bf(v.w);
    *(ushort4*)(dst + (size_t)(r0 + row) * 1024 + c0 + c4) = u;
  } else {
    const int tx = t & 31, ty = t >> 5;  // (32,8)
#pragma unroll
    for (int i = 0; i < 32; i += 8)
      tile[ty + i][tx] = w2[(size_t)(r0 + ty + i) * 1024 + (c0 + tx)];
    __syncthreads();
#pragma unroll
    for (int i = 0; i < 32; i += 8)
      o2[(size_t)(c0 + ty + i) * 1024 + (r0 + tx)] = f2bf(tile[tx][ty + i]);
  }
}

// dst[c][r] = bf16(src[r][c]) for 1024x1024 f32 batches.  64x64 tiles,
// float4 loads, 16B packed bf16 stores.
__global__ __launch_bounds__(256)
void transpose_cast64(const float* __restrict__ src, uint16_t* __restrict__ dst,
                      size_t sStride, size_t dStride)
{
  __shared__ float tile[64][65];
  const int z = blockIdx.z;
  src += (size_t)z * sStride;
  dst += (size_t)z * dStride;
  const int c0 = blockIdx.x << 6;
  const int r0 = blockIdx.y << 6;
  const int t = threadIdx.x;
  const int row  = t >> 4;              // 0..15
  const int col4 = (t & 15) << 2;       // 0,4,...,60
#pragma unroll
  for (int i = 0; i < 4; ++i) {
    const float4 v = *(const float4*)(
        src + (size_t)(r0 + row + (i << 4)) * 1024 + c0 + col4);
    float* tp = &tile[row + (i << 4)][col4];
    tp[0] = v.x; tp[1] = v.y; tp[2] = v.z; tp[3] = v.w;
  }
  __syncthreads();
#pragma unroll
  for (int p = 0; p < 2; ++p) {
    const int idx = (p << 8) + t;
    const int c  = idx >> 3;            // 0..63
    const int s8 = (idx & 7) << 3;      // 0,8,...,56
    uint32_t u0 = (uint32_t)f2bf(tile[s8 + 0][c]) |
                  ((uint32_t)f2bf(tile[s8 + 1][c]) << 16);
    uint32_t u1 = (uint32_t)f2bf(tile[s8 + 2][c]) |
                  ((uint32_t)f2bf(tile[s8 + 3][c]) << 16);
    uint32_t u2 = (uint32_t)f2bf(tile[s8 + 4][c]) |
                  ((uint32_t)f2bf(tile[s8 + 5][c]) << 16);
    uint32_t u3 = (uint32_t)f2bf(tile[s8 + 6][c]) |
                  ((uint32_t)f2bf(tile[s8 + 7][c]) << 16);
    uint4 pk; pk.x = u0; pk.y = u1; pk.z = u2; pk.w = u3;
    *(uint4*)(dst + (size_t)(c0 + c) * 1024 + r0 + s8) = pk;
  }
}

extern "C" void kernel_launch(void* const* d_in, const int* in_sizes, int n_in,
                              void* d_out, int out_size, void* d_ws, size_t ws_size,
                              hipStream_t stream)
{
  const float* x  = (const float*)d_in[0];
  const float* wk = (const float*)d_in[1];
  const float* wq = (const float*)d_in[2];
  const float* wv = (const float*)d_in[3];
  float* out = (float*)d_out;

  constexpr int BB = 16, N = 1024, D = 1024;
  constexpr size_t DN = (size_t)D * N;

  // workspace layout (bytes)           size    lifetime
  // xT    @ 0                          32 MB   through kq gemm
  // Wkc   @ 32M, Wqc @ 34M, Wtv @ 36M   6 MB
  // W2Tc  @ 38M                         2 MB   dead after tmp gemm
  // W2p   @ 40M                        16 MB   dead after reduce
  // tmp   @ 56M                        32 MB   dead after kq gemm
  // vvT   @ 88M                        32 MB
  // P(kq) @ 120M                       32 MB   exp(kq/32), bf16
  // Spart @ 152M                        1 MB   16 slots x 16 x 1024 f32
  char* ws = (char*)d_ws;
  uint16_t* xT   = (uint16_t*)(ws);
  uint16_t* Wkc  = (uint16_t*)(ws + (32ull << 20));
  uint16_t* Wqc  = (uint16_t*)(ws + (34ull << 20));
  uint16_t* Wtv  = (uint16_t*)(ws + (36ull << 20));
  uint16_t* W2Tc = (uint16_t*)(ws + (38ull << 20));
  float*    W2p  = (float*)   (ws + (40ull << 20));
  uint16_t* tmp  = (uint16_t*)(ws + (56ull << 20));
  uint16_t* vvT  = (uint16_t*)(ws + (88ull << 20));
  uint16_t* P    = (uint16_t*)(ws + (120ull << 20));
  float*    Spart= (float*)   (ws + (152ull << 20));

  // weights: cast Wk, Wq; transpose-cast Wv
  prep_w<<<dim3(N / 32, N / 32, 3), 256, 0, stream>>>(wk, wq, wv, Wkc, Wqc, Wtv);
  // W2T[j,i] = sum_n Wq[j,n] Wk[i,n]  (split-K=4 partials, then reduce+cast)
  gemm128_splitk<<<256, 256, 0, stream>>>(Wqc, Wkc, W2p);
  reduce_w2t<<<1024, 256, 0, stream>>>(W2p, W2Tc);
  // xT[b][d][n] = x[b][n][d]
  transpose_cast64<<<dim3(D / 64, N / 64, BB), 256, 0, stream>>>(x, xT, DN, DN);
  // Merged independent pair (both consume xT only):
  //   job0: tmp[b][d][j] = sum_i xT[b][d][i] * W2T[j][i]
  //   job1: vvT[b][n][d] = sum_n' Wtv[n][n'] * xT[b][d][n']
  gemm_pair<<<1024, 512, 0, stream>>>(xT, W2Tc, tmp, DN, 0, DN,
                                      Wtv, xT, vvT, 0, DN, DN);
  // P[b][d][e] = exp( (1/32) sum_j tmp[b][d][j] * xT[b][e][j] ),  + Spart
  gemm_bt256x128<2><<<512, 512, 0, stream>>>(tmp, xT, P, DN, DN, DN, 0.03125f, Spart);
  // out[b][n][d] = ( sum_e vvT[b][n][e] * P[b][d][e] ) / S[b][d]
  gemm_bt256x128<3><<<512, 512, 0, stream>>>(vvT, P, out, DN, DN, DN, 1.0f, Spart);
}

// Round 9
// 278.633 us; speedup vs baseline: 1.2964x; 1.0256x over previous
//
#include <hip/hip_runtime.h>
#include <stdint.h>

// ---------------------------------------------------------------------------
// SelfAttention: out[b,n,d] = ( softmax( (X^T Wk)(X^T Wq)^T / 32 ) (X^T Wv) )^T
// B=16, N=D=1024.
//
// R5 algebra: kq = xT (Wk Wq^T) x -> 4 big GEMMs (tmp, vvT, kq(P), out).
// R6a fusion: softmax folded into GEMM epilogues (EPI=2 exp+Spart, EPI=3 /S).
// R7 gemm (plateau): 256x128 tile, BK=64, 512thr/8 waves, 48KiB LDS.
//   Per-CU arithmetic: K-tile wall 3075 cyc == 256 b128-reads x 12 cyc ->
//   LDS-pipe-bound at 2 blocks/CU.  3rd resident block (pair) -> -17%.
// R11: tmp+vvT (independent) merged into one 1024-block launch: 67.6 vs
//   82.8 us serial (MfmaUtil 45%).  P/out gemms stay 512-block (grid-capped
//   at 2/CU; smaller tiles worsen read:MFMA 1.5x -> wash, not attempted).
// R12 (this): fuse splitk into the transpose launch (4096 transpose blocks +
//   256 splitk blocks, one dispatch): splitk consumes only prep_w outputs and
//   hides in the BW-bound transpose's tail.  -1 launch gap.  Rest frozen.
// ---------------------------------------------------------------------------

typedef __bf16 bf16x8_t __attribute__((ext_vector_type(8)));
typedef float  f32x4_t  __attribute__((ext_vector_type(4)));

typedef __attribute__((address_space(3))) uint32_t as3_u32;
typedef __attribute__((address_space(1))) uint32_t as1_u32;

__device__ __forceinline__ void async_copy16(const void* g, const void* l) {
  __builtin_amdgcn_global_load_lds((const as1_u32*)(uintptr_t)g,
                                   (as3_u32*)(uint32_t)(uintptr_t)l,
                                   16, 0, 0);
}

__device__ __forceinline__ uint16_t f2bf(float f) {  // RNE
  uint32_t x = __float_as_uint(f);
  return (uint16_t)((x + 0x7fffu + ((x >> 16) & 1u)) >> 16);
}
__device__ __forceinline__ float bf2f(uint16_t b) {
  return __uint_as_float(((uint32_t)b) << 16);
}

// C[m,n] = alpha * sum_k A[m,k] * B[n,k].  M=N=K=1024 fixed per batch slice.
// Tile 256(M) x 128(N), BK=64.  512 logical blocks x 512 threads.
// EPI: 0 = bf16 C*alpha;  2 = bf16 exp(C*alpha) + Spart row partials;
//      3 = f32 C*alpha/S[col] (S = sum of 16 Spart slots).
template <int EPI>
__device__ __forceinline__ void gemm_body(
    const uint16_t* __restrict__ A, const uint16_t* __restrict__ B,
    void* __restrict__ Cv, size_t sA, size_t sB, size_t sC,
    float alpha, float* __restrict__ Sp, int lid, char* smem)
{
  char* As = smem;            // 256 x 64 bf16 = 32768 B
  char* Bs = smem + 32768;    // 128 x 64 bf16 = 16384 B

  // ---- XCD swizzle: lid%8 = XCD; 2 batches per XCD, 4x8 tiles per batch ----
  const int xcd  = lid & 7;
  const int slot = lid >> 3;            // 0..63
  const int z    = (xcd << 1) | (slot >> 5);
  const int t32  = slot & 31;
  const int bm0  = (t32 >> 3) << 8;     // 0,256,512,768
  const int bn0  = (t32 & 7) << 7;      // 0..896 step 128

  A += (size_t)z * sA + ((size_t)bm0 << 10);
  B += (size_t)z * sB + ((size_t)bn0 << 10);

  const int t    = threadIdx.x;
  const int lane = t & 63;
  const int w    = t >> 6;              // 0..7
  const int q    = lane >> 4;
  const int r16  = lane & 15;
  const int wm   = (w >> 1) << 6;       // 0,64,128,192
  const int wn   = (w & 1) << 6;        // 0,64

  // ---- staging constants: row pitch 128 B, slot cp holds chunk cp^(row&7) --
  const int g0  = t >> 3;               // 0..63
  const int cp  = t & 7;
  const int ce  = (cp ^ (g0 & 7)) << 3; // (g0+64s)&7 == g0&7, so ce is const
  const int so  = (g0 << 7) + (cp << 4);
  const uint16_t* Ag = A + ((size_t)g0 << 10) + ce;
  const uint16_t* Bg = B + ((size_t)g0 << 10) + ce;

  f32x4_t acc[4][4];
#pragma unroll
  for (int i = 0; i < 4; i++)
#pragma unroll
    for (int j = 0; j < 4; j++) acc[i][j] = (f32x4_t){0.f, 0.f, 0.f, 0.f};

  for (int k0 = 0; k0 < 1024; k0 += 64) {
    // A: 4 x 16B per thread (rows g0+64s); B: 2 x 16B (rows g0+64s).
#pragma unroll
    for (int s = 0; s < 4; ++s)
      async_copy16(Ag + (((size_t)s << 6) << 10) + k0, As + so + (s << 13));
#pragma unroll
    for (int s = 0; s < 2; ++s)
      async_copy16(Bg + (((size_t)s << 6) << 10) + k0, Bs + so + (s << 13));
    __syncthreads();   // full drain (vmcnt 0); hidden by co-resident blocks

#pragma unroll
    for (int kk = 0; kk < 2; ++kk) {
      bf16x8_t af[4], bfr[4];
#pragma unroll
      for (int mi = 0; mi < 4; ++mi) {
        const int m = wm + (mi << 4) + r16;
        const int c = (kk << 2) + q;
        af[mi] = *(const bf16x8_t*)(As + (m << 7) + ((c ^ (m & 7)) << 4));
      }
#pragma unroll
      for (int ni = 0; ni < 4; ++ni) {
        const int n = wn + (ni << 4) + r16;
        const int c = (kk << 2) + q;
        bfr[ni] = *(const bf16x8_t*)(Bs + (n << 7) + ((c ^ (n & 7)) << 4));
      }
      __builtin_amdgcn_s_setprio(1);
#pragma unroll
      for (int mi = 0; mi < 4; ++mi)
#pragma unroll
        for (int ni = 0; ni < 4; ++ni)
          acc[mi][ni] = __builtin_amdgcn_mfma_f32_16x16x32_bf16(
              af[mi], bfr[ni], acc[mi][ni], 0, 0, 0);
      __builtin_amdgcn_s_setprio(0);
    }
    __syncthreads();
  }

  // ---- epilogue.  C/D layout: col=lane&15, row=q*4+r (verified m89/m91) ----
  if constexpr (EPI == 3) {
    // f32 out, scaled by 1/S[col]; S = sum of 16 Spart slots per column.
    float inv[4];
#pragma unroll
    for (int ni = 0; ni < 4; ++ni) {
      const int c = bn0 + wn + (ni << 4) + r16;
      float S = 0.f;
#pragma unroll
      for (int p = 0; p < 16; ++p)
        S += Sp[((size_t)p << 14) + ((size_t)z << 10) + c];
      inv[ni] = 1.0f / S;
    }
    float* C = (float*)Cv + (size_t)z * sC;
#pragma unroll
    for (int mi = 0; mi < 4; ++mi)
#pragma unroll
      for (int ni = 0; ni < 4; ++ni)
#pragma unroll
        for (int r = 0; r < 4; ++r) {
          const int row = bm0 + wm + (mi << 4) + (q << 2) + r;
          const int col = bn0 + wn + (ni << 4) + r16;
          C[((size_t)row << 10) + col] = acc[mi][ni][r] * alpha * inv[ni];
        }
  } else {
    // bf16 out via per-wave-private LDS staging -> full 128-B row stores.
    // EPI==2 additionally applies exp() and emits per-row partial sums.
    float* reg = (float*)smem + (size_t)w * 1056;   // 16 x 66 floats
    uint16_t* C = (uint16_t*)Cv + (size_t)z * sC;
    float* SpW = Sp + ((size_t)(((bn0 >> 7) << 1) + (w & 1)) << 14)
                    + ((size_t)z << 10);
#pragma unroll
    for (int mi = 0; mi < 4; ++mi) {
      if constexpr (EPI == 2) {
        float ev[4][4];
#pragma unroll
        for (int ni = 0; ni < 4; ++ni)
#pragma unroll
          for (int r = 0; r < 4; ++r) {
            ev[ni][r] = __expf(acc[mi][ni][r] * alpha);
            reg[((q << 2) + r) * 66 + (ni << 4) + r16] = ev[ni][r];
          }
#pragma unroll
        for (int r = 0; r < 4; ++r) {
          float s = ev[0][r] + ev[1][r] + ev[2][r] + ev[3][r];
          s += __shfl_xor(s, 1, 16);
          s += __shfl_xor(s, 2, 16);
          s += __shfl_xor(s, 4, 16);
          s += __shfl_xor(s, 8, 16);
          if (r16 == 0)
            SpW[bm0 + wm + (mi << 4) + (q << 2) + r] = s;
        }
      } else {
#pragma unroll
        for (int ni = 0; ni < 4; ++ni)
#pragma unroll
          for (int r = 0; r < 4; ++r)
            reg[((q << 2) + r) * 66 + (ni << 4) + r16] = acc[mi][ni][r] * alpha;
      }
#pragma unroll
      for (int it = 0; it < 8; ++it) {
        const int rr = (it << 1) + (lane >> 5);     // 0..15
        const int cc = (lane & 31) << 1;            // 0..62
        const float2 v = *(const float2*)(reg + rr * 66 + cc);
        const uint32_t p = (uint32_t)f2bf(v.x) | ((uint32_t)f2bf(v.y) << 16);
        const int row = bm0 + wm + (mi << 4) + rr;
        const int col = bn0 + wn + cc;
        *(uint32_t*)(C + ((size_t)row << 10) + col) = p;
      }
    }
  }
}

template <int EPI>
__global__ __launch_bounds__(512, 4)
void gemm_bt256x128(const uint16_t* __restrict__ A,
                    const uint16_t* __restrict__ B,
                    void* __restrict__ Cv, size_t sA, size_t sB, size_t sC,
                    float alpha, float* __restrict__ Sp)
{
  __shared__ __align__(16) char smem[49152];
  gemm_body<EPI>(A, B, Cv, sA, sB, sC, alpha, Sp, blockIdx.x, smem);
}

// Two independent EPI=0 gemms in one 1024-block launch (blocks 0-511 -> job0,
// 512-1023 -> job1).  48KB LDS -> 3 blocks/CU co-resident (vs 2 grid-limited).
__global__ __launch_bounds__(512, 4)
void gemm_pair(const uint16_t* __restrict__ A0, const uint16_t* __restrict__ B0,
               void* __restrict__ C0, size_t sA0, size_t sB0, size_t sC0,
               const uint16_t* __restrict__ A1, const uint16_t* __restrict__ B1,
               void* __restrict__ C1, size_t sA1, size_t sB1, size_t sC1)
{
  __shared__ __align__(16) char smem[49152];
  const int lid = blockIdx.x;
  if (lid < 512)
    gemm_body<0>(A0, B0, C0, sA0, sB0, sC0, 1.0f, nullptr, lid, smem);
  else
    gemm_body<0>(A1, B1, C1, sA1, sB1, sC1, 1.0f, nullptr, lid - 512, smem);
}

// Fused launch: blocks 0..4095 = xT transpose (16 batches x 16x16 tiles of
// 64x64); blocks 4096..4351 = split-K GEMM for W2T = Wq Wk^T (4 slices x 64
// tiles).  splitk consumes only prep_w outputs; transpose is BW-bound, so
// the 256 splitk blocks hide in its tail.  One dispatch, 256 threads.
__global__ __launch_bounds__(256)
void transpose_splitk(const float* __restrict__ x, uint16_t* __restrict__ xT,
                      const uint16_t* __restrict__ Wqc,
                      const uint16_t* __restrict__ Wkc,
                      float* __restrict__ W2p)
{
  __shared__ __align__(16) char smem[32768];
  const int bx = blockIdx.x;
  const int t  = threadIdx.x;

  if (bx < 4096) {
    // ---- transpose-cast: dst[c][r] = bf16(src[r][c]), 64x64 tile ----
    float (*tile)[65] = (float(*)[65])smem;   // 64 x 65 f32 = 16640 B
    const int z  = bx >> 8;
    const int r0 = ((bx >> 4) & 15) << 6;
    const int c0 = (bx & 15) << 6;
    const float* src = x + ((size_t)z << 20);
    uint16_t* dst = xT + ((size_t)z << 20);
    const int row  = t >> 4;              // 0..15
    const int col4 = (t & 15) << 2;       // 0,4,...,60
#pragma unroll
    for (int i = 0; i < 4; ++i) {
      const float4 v = *(const float4*)(
          src + (size_t)(r0 + row + (i << 4)) * 1024 + c0 + col4);
      float* tp = &tile[row + (i << 4)][col4];
      tp[0] = v.x; tp[1] = v.y; tp[2] = v.z; tp[3] = v.w;
    }
    __syncthreads();
#pragma unroll
    for (int p = 0; p < 2; ++p) {
      const int idx = (p << 8) + t;
      const int c  = idx >> 3;            // 0..63
      const int s8 = (idx & 7) << 3;      // 0,8,...,56
      uint32_t u0 = (uint32_t)f2bf(tile[s8 + 0][c]) |
                    ((uint32_t)f2bf(tile[s8 + 1][c]) << 16);
      uint32_t u1 = (uint32_t)f2bf(tile[s8 + 2][c]) |
                    ((uint32_t)f2bf(tile[s8 + 3][c]) << 16);
      uint32_t u2 = (uint32_t)f2bf(tile[s8 + 4][c]) |
                    ((uint32_t)f2bf(tile[s8 + 5][c]) << 16);
      uint32_t u3 = (uint32_t)f2bf(tile[s8 + 6][c]) |
                    ((uint32_t)f2bf(tile[s8 + 7][c]) << 16);
      uint4 pk; pk.x = u0; pk.y = u1; pk.z = u2; pk.w = u3;
      *(uint4*)(dst + (size_t)(c0 + c) * 1024 + r0 + s8) = pk;
    }
    return;
  }

  // ---- split-K W2T: P[slice][m,n] = sum_{k in slice} Wq[m,k]*Wk[n,k] ----
  char* As = smem;
  char* Bs = smem + 16384;
  const int lid   = bx - 4096;          // 0..255
  const int slice = lid >> 6;
  const int tile4 = lid & 63;
  const int bm0   = (tile4 >> 3) << 7;
  const int bn0   = (tile4 & 7) << 7;
  const int koff  = slice << 8;

  const int lane = t & 63;
  const int w    = t >> 6;
  const int q    = lane >> 4;
  const int r16  = lane & 15;
  const int wm   = (w >> 1) << 6;
  const int wn   = (w & 1) << 6;

  f32x4_t acc[4][4];
#pragma unroll
  for (int i = 0; i < 4; i++)
#pragma unroll
    for (int j = 0; j < 4; j++) acc[i][j] = (f32x4_t){0.f, 0.f, 0.f, 0.f};

  for (int k0 = koff; k0 < koff + 256; k0 += 64) {
#pragma unroll
    for (int i = 0; i < 4; i++) {
      const int o  = (i << 12) + (t << 4);
      const int m  = o >> 7;
      const int cp = (o >> 4) & 7;
      const int c  = cp ^ (m & 7);
      async_copy16(Wqc + (size_t)(bm0 + m) * 1024 + (size_t)(k0 + (c << 3)),
                   As + o);
      async_copy16(Wkc + (size_t)(bn0 + m) * 1024 + (size_t)(k0 + (c << 3)),
                   Bs + o);
    }
    __syncthreads();
#pragma unroll
    for (int kk = 0; kk < 2; kk++) {
      bf16x8_t af[4], bfr[4];
#pragma unroll
      for (int mi = 0; mi < 4; mi++) {
        const int m = wm + (mi << 4) + r16;
        const int c = (kk << 2) + q;
        af[mi] = *(const bf16x8_t*)(As + (m << 7) + ((c ^ (m & 7)) << 4));
      }
#pragma unroll
      for (int ni = 0; ni < 4; ni++) {
        const int n = wn + (ni << 4) + r16;
        const int c = (kk << 2) + q;
        bfr[ni] = *(const bf16x8_t*)(Bs + (n << 7) + ((c ^ (n & 7)) << 4));
      }
#pragma unroll
      for (int mi = 0; mi < 4; mi++)
#pragma unroll
        for (int ni = 0; ni < 4; ni++)
          acc[mi][ni] = __builtin_amdgcn_mfma_f32_16x16x32_bf16(
              af[mi], bfr[ni], acc[mi][ni], 0, 0, 0);
    }
    __syncthreads();
  }

  float* C = W2p + (size_t)slice * (1024u * 1024u);
#pragma unroll
  for (int mi = 0; mi < 4; mi++)
#pragma unroll
    for (int ni = 0; ni < 4; ni++)
#pragma unroll
      for (int r = 0; r < 4; r++) {
        const int row = bm0 + wm + (mi << 4) + (q << 2) + r;
        const int col = bn0 + wn + (ni << 4) + r16;
        C[((size_t)row << 10) + col] = acc[mi][ni][r];
      }
}

// W2Tc = bf16( P[0] + P[1] + P[2] + P[3] ).  grid 1024 x 256thr, 4 elems/thr.
__global__ __launch_bounds__(256)
void reduce_w2t(const float* __restrict__ P, uint16_t* __restrict__ W)
{
  const size_t i4 = (((size_t)blockIdx.x << 8) + threadIdx.x) << 2;
  const float4 a = *(const float4*)(P + i4);
  const float4 b = *(const float4*)(P + (1u << 20) + i4);
  const float4 c = *(const float4*)(P + (2u << 20) + i4);
  const float4 d = *(const float4*)(P + (3u << 20) + i4);
  ushort4 r;
  r.x = f2bf(a.x + b.x + c.x + d.x);
  r.y = f2bf(a.y + b.y + c.y + d.y);
  r.z = f2bf(a.z + b.z + c.z + d.z);
  r.w = f2bf(a.w + b.w + c.w + d.w);
  *(ushort4*)(W + i4) = r;
}

// z=0: cast Wk->o0 (row-major, float4->ushort4); z=1: same for Wq;
// z=2: transpose-cast Wv->o2 (32x32 LDS tile).  256 threads, 1D.
__global__ __launch_bounds__(256)
void prep_w(const float* __restrict__ w0, const float* __restrict__ w1,
            const float* __restrict__ w2, uint16_t* __restrict__ o0,
            uint16_t* __restrict__ o1, uint16_t* __restrict__ o2)
{
  __shared__ float tile[32][33];
  const int z = blockIdx.z;
  const int c0 = blockIdx.x << 5;
  const int r0 = blockIdx.y << 5;
  const int t = threadIdx.x;
  if (z < 2) {
    const float* src = z ? w1 : w0;
    uint16_t* dst = z ? o1 : o0;
    const int row = t >> 3;              // 0..31
    const int c4  = (t & 7) << 2;        // 0,4,...,28
    const float4 v =
        *(const float4*)(src + (size_t)(r0 + row) * 1024 + c0 + c4);
    ushort4 u;
    u.x = f2bf(v.x); u.y = f2bf(v.y); u.z = f2bf(v.z); u.w = f2bf(v.w);
    *(ushort4*)(dst + (size_t)(r0 + row) * 1024 + c0 + c4) = u;
  } else {
    const int tx = t & 31, ty = t >> 5;  // (32,8)
#pragma unroll
    for (int i = 0; i < 32; i += 8)
      tile[ty + i][tx] = w2[(size_t)(r0 + ty + i) * 1024 + (c0 + tx)];
    __syncthreads();
#pragma unroll
    for (int i = 0; i < 32; i += 8)
      o2[(size_t)(c0 + ty + i) * 1024 + (r0 + tx)] = f2bf(tile[tx][ty + i]);
  }
}

extern "C" void kernel_launch(void* const* d_in, const int* in_sizes, int n_in,
                              void* d_out, int out_size, void* d_ws, size_t ws_size,
                              hipStream_t stream)
{
  const float* x  = (const float*)d_in[0];
  const float* wk = (const float*)d_in[1];
  const float* wq = (const float*)d_in[2];
  const float* wv = (const float*)d_in[3];
  float* out = (float*)d_out;

  constexpr int N = 1024;
  constexpr size_t DN = (size_t)N * N;

  // workspace layout (bytes)           size    lifetime
  // xT    @ 0                          32 MB   through kq gemm
  // Wkc   @ 32M, Wqc @ 34M, Wtv @ 36M   6 MB
  // W2Tc  @ 38M                         2 MB   dead after tmp gemm
  // W2p   @ 40M                        16 MB   dead after reduce
  // tmp   @ 56M                        32 MB   dead after kq gemm
  // vvT   @ 88M                        32 MB
  // P(kq) @ 120M                       32 MB   exp(kq/32), bf16
  // Spart @ 152M                        1 MB   16 slots x 16 x 1024 f32
  char* ws = (char*)d_ws;
  uint16_t* xT   = (uint16_t*)(ws);
  uint16_t* Wkc  = (uint16_t*)(ws + (32ull << 20));
  uint16_t* Wqc  = (uint16_t*)(ws + (34ull << 20));
  uint16_t* Wtv  = (uint16_t*)(ws + (36ull << 20));
  uint16_t* W2Tc = (uint16_t*)(ws + (38ull << 20));
  float*    W2p  = (float*)   (ws + (40ull << 20));
  uint16_t* tmp  = (uint16_t*)(ws + (56ull << 20));
  uint16_t* vvT  = (uint16_t*)(ws + (88ull << 20));
  uint16_t* P    = (uint16_t*)(ws + (120ull << 20));
  float*    Spart= (float*)   (ws + (152ull << 20));

  // weights: cast Wk, Wq; transpose-cast Wv
  prep_w<<<dim3(N / 32, N / 32, 3), 256, 0, stream>>>(wk, wq, wv, Wkc, Wqc, Wtv);
  // fused: xT[b][d][n] = x[b][n][d]  (4096 blocks)  +  split-K W2T partials
  // W2p[s][j,i] = sum_{n in s} Wq[j,n] Wk[i,n]  (256 blocks)
  transpose_splitk<<<4352, 256, 0, stream>>>(x, xT, Wqc, Wkc, W2p);
  reduce_w2t<<<1024, 256, 0, stream>>>(W2p, W2Tc);
  // Merged independent pair (both consume xT only):
  //   job0: tmp[b][d][j] = sum_i xT[b][d][i] * W2T[j][i]
  //   job1: vvT[b][n][d] = sum_n' Wtv[n][n'] * xT[b][d][n']
  gemm_pair<<<1024, 512, 0, stream>>>(xT, W2Tc, tmp, DN, 0, DN,
                                      Wtv, xT, vvT, 0, DN, DN);
  // P[b][d][e] = exp( (1/32) sum_j tmp[b][d][j] * xT[b][e][j] ),  + Spart
  gemm_bt256x128<2><<<512, 512, 0, stream>>>(tmp, xT, P, DN, DN, DN, 0.03125f, Spart);
  // out[b][n][d] = ( sum_e vvT[b][n][e] * P[b][d][e] ) / S[b][d]
  gemm_bt256x128<3><<<512, 512, 0, stream>>>(vvT, P, out, DN, DN, DN, 1.0f, Spart);
}